// Round 9
// baseline (229.533 us; speedup 1.0000x reference)
//
#include <hip/hip_runtime.h>

// AutoregressiveLSTM: B=16384, T=100, HID=10, IN=OUT=4, P=5, Tp=96.
// Round 9: 20 lanes per batch (2 lanes per hidden unit) -> 3 batches/wave,
// 5464 waves (2x round-8) = 5.33 waves/SIMD for stall coverage.
// Even lane 2m owns gate rows {i[m], g[m+20]}; odd lane 2m+1 owns {f[m+10],
// o[m+30]}. Sign-folded pre-scales make the activation code divergence-free:
//   a0 = rcp(1+exp2(gA))            -> sigma(i) on even, sigma(f) on odd
//   a1 = fma(sel_s, rcp(1+exp2(gB)), sel_b) -> tanh(g) even / sigma(o) odd
//   shfl_xor(a0*a1, 1) delivers sigma(i)*tanh(g) to the odd lane, which owns
//   c and h (h written to LDS by odd lanes; all lanes read rows back).
// All cells use folded W_comb = W_hh + W_ih@W_lin (R5-proven); main cell adds
// the rank-4 correction wih@(x - y_prev), y_prev = y[t-1][p=0] from s_y.
// W_lin lives in LDS (broadcast reads); y-phase = exactly 1 output per lane.

#define HIDN 10
#define INPN 4
#define OUTN 4
#define PN   5
#define TN   100
#define TPN  96
#define BN   16384
#define GPB  6    // batches per 128-thread block (3 per wave)

typedef float v2f __attribute__((ext_vector_type(2)));

#define PIN(x) asm volatile("" : "+v"(x))

__device__ __forceinline__ float rcpf_(float v) { return __builtin_amdgcn_rcpf(v); }
__device__ __forceinline__ float e2_(float v)   { return __builtin_amdgcn_exp2f(v); }

#define K2L2E 2.88539008177792681472f  // 2*log2(e), for tanh(c)

__global__ __launch_bounds__(128, 5) void lstm_ar_kernel(
    const float* __restrict__ x,      // [B, T, IN]
    const float* __restrict__ W_ih,   // [40, 4]
    const float* __restrict__ W_hh,   // [40, 10]
    const float* __restrict__ b_ih,   // [40]
    const float* __restrict__ b_hh,   // [40]
    const float* __restrict__ W_lin,  // [4, 10]
    const float* __restrict__ b_lin,  // [4]
    float* __restrict__ out)          // [B*Tp*P*OUT] ++ [B*HID]
{
    // h rows padded to 12 floats (48B): conflict-spread for the 4-row y reads.
    __shared__ __align__(16) float s_h[GPB][PN][12];
    __shared__ __align__(16) float s_wlin[OUTN][12];
    __shared__ __align__(16) float s_y[GPB][4];     // y[t-1][p=0] per slot

    const int tid = threadIdx.x;
    const int wid = tid >> 6;
    const int wl  = tid & 63;

    // stage W_lin (both waves write identical values -- benign, no sync needed)
    if (wl < 48) {
        const int r = wl / 12, cc = wl - r * 12;
        s_wlin[r][cc] = (cc < HIDN) ? W_lin[r * HIDN + cc] : 0.0f;
    }

    const int grp = wl / 20;          // 0..2 valid; 3 = idle lanes 60-63
    const int l   = wl - grp * 20;    // 0..19 within group
    const int m   = l >> 1;           // hidden unit 0..9
    const int odd = l & 1;
    const int slot  = wid * 3 + grp;  // 0..5
    const int batch = blockIdx.x * GPB + slot;
    __builtin_amdgcn_wave_barrier();
    if (grp >= 3 || batch >= BN) return;

    // ---- per-lane folded weights for my TWO gate rows ----
    const float L2E = 1.44269504088896340736f;
    const int rA = m + (odd ? 10 : 0);        // i-row (even) / f-row (odd)
    const int rB = m + (odd ? 30 : 20);       // g-row (even) / o-row (odd)
    const float sA = -L2E;                    // sigma via rcp(1+exp2(+gA))
    const float sB = odd ? -L2E : 2.0f * L2E; // sigma(o) / tanh(g) forms
    const float sel_s = odd ? 1.0f : -2.0f;
    const float sel_b = odd ? 0.0f : 1.0f;

    v2f wcA[5], wcB[5], wihA[2], wihB[2];
    float bA, bB;
    {
        float wa[INPN], wb[INPN];
        #pragma unroll
        for (int q = 0; q < INPN; ++q) { wa[q] = W_ih[rA * INPN + q]; wb[q] = W_ih[rB * INPN + q]; }
        float ba = b_ih[rA] + b_hh[rA];
        float bb = b_ih[rB] + b_hh[rB];
        #pragma unroll
        for (int q = 0; q < INPN; ++q) { ba += wa[q] * b_lin[q]; bb += wb[q] * b_lin[q]; }
        #pragma unroll
        for (int k = 0; k < HIDN; ++k) {
            float ca = W_hh[rA * HIDN + k];
            float cb = W_hh[rB * HIDN + k];
            #pragma unroll
            for (int q = 0; q < INPN; ++q) {
                ca += wa[q] * W_lin[q * HIDN + k];
                cb += wb[q] * W_lin[q * HIDN + k];
            }
            if (k & 1) { wcA[k >> 1].y = ca * sA; wcB[k >> 1].y = cb * sB; }
            else       { wcA[k >> 1].x = ca * sA; wcB[k >> 1].x = cb * sB; }
        }
        #pragma unroll
        for (int q = 0; q < INPN; ++q) {
            if (q & 1) { wihA[q >> 1].y = wa[q] * sA; wihB[q >> 1].y = wb[q] * sB; }
            else       { wihA[q >> 1].x = wa[q] * sA; wihB[q >> 1].x = wb[q] * sB; }
        }
        bA = ba * sA;
        bB = bb * sB;
    }
    #pragma unroll
    for (int k = 0; k < 5; ++k) { PIN(wcA[k]); PIN(wcB[k]); }
    PIN(wihA[0]); PIN(wihA[1]); PIN(wihB[0]); PIN(wihB[1]);
    PIN(bA); PIN(bB);

    // y-phase: lane l outputs y[t][pm][om]
    const int pm = l >> 2;           // rollout step 0..4
    const int om = l & 3;            // output column
    const float yb = b_lin[om];

    const float* xb   = x + (long)batch * TN * INPN;
    float*       outb = out + (long)batch * TPN * PN * OUTN;

    float cm = 0.0f;                 // valid on odd lanes
    v2f hm[5];
    #pragma unroll
    for (int k = 0; k < 5; ++k) hm[k] = v2f{0.0f, 0.0f};

    if (l < 4) s_y[slot][l] = b_lin[l];   // y_prev seed (h=0)
    __builtin_amdgcn_wave_barrier();

    // gates -> h_new; updates c (both valid on ODD lanes only; even = benign garbage)
    auto ACT = [&](float gA, float gB, float& c) -> float {
        float a0 = rcpf_(1.0f + e2_(gA));
        float r1 = rcpf_(1.0f + e2_(gB));
        float a1 = fmaf(sel_s, r1, sel_b);
        float pr = a0 * a1;                       // even: sigma(i)*tanh(g)
        float sw = __shfl_xor(pr, 1, 64);         // odd receives it
        c = fmaf(a0, c, sw);                      // odd: sigma(f)*c + p
        float th = fmaf(-2.0f, rcpf_(1.0f + e2_(c * K2L2E)), 1.0f);
        return a1 * th;                           // odd: sigma(o)*tanh(c)
    };

    for (int t = 0; t < TPN; ++t) {
        const float4 xv = *(const float4*)(xb + t * INPN);

        // ---- MAIN: gates = wc@h + b + wih@(x - y_prev) ----
        {
            float4 yp = *(const float4*)&s_y[slot][0];
            v2f dx0 = v2f{xv.x - yp.x, xv.y - yp.y};
            v2f dx1 = v2f{xv.z - yp.z, xv.w - yp.w};
            v2f aA = v2f{bA, 0.0f}, aB = v2f{bB, 0.0f};
            aA = __builtin_elementwise_fma(wihA[0], dx0, aA);
            aB = __builtin_elementwise_fma(wihB[0], dx0, aB);
            aA = __builtin_elementwise_fma(wihA[1], dx1, aA);
            aB = __builtin_elementwise_fma(wihB[1], dx1, aB);
            #pragma unroll
            for (int k = 0; k < 5; ++k) {
                aA = __builtin_elementwise_fma(wcA[k], hm[k], aA);
                aB = __builtin_elementwise_fma(wcB[k], hm[k], aB);
            }
            float hn = ACT(aA.x + aA.y, aB.x + aB.y, cm);
            if (odd) s_h[slot][0][m] = hn;
        }
        __builtin_amdgcn_wave_barrier();
        {
            const v2f* hp = (const v2f*)&s_h[slot][0][0];
            #pragma unroll
            for (int k = 0; k < 5; ++k) hm[k] = hp[k];   // h_t
        }

        // ---- ROLLOUT p=1..4: gates = wc@h_{p-1} + b ----
        float cr = cm;
        v2f hr[5];
        #pragma unroll
        for (int k = 0; k < 5; ++k) hr[k] = hm[k];
        #pragma unroll
        for (int p = 1; p < PN; ++p) {
            v2f aA = v2f{bA, 0.0f}, aB = v2f{bB, 0.0f};
            #pragma unroll
            for (int k = 0; k < 5; ++k) {
                aA = __builtin_elementwise_fma(wcA[k], hr[k], aA);
                aB = __builtin_elementwise_fma(wcB[k], hr[k], aB);
            }
            float hn = ACT(aA.x + aA.y, aB.x + aB.y, cr);
            if (odd) s_h[slot][p][m] = hn;
            __builtin_amdgcn_wave_barrier();
            if (p < PN - 1) {
                const v2f* hp = (const v2f*)&s_h[slot][p][0];
                #pragma unroll
                for (int k = 0; k < 5; ++k) hr[k] = hp[k];
            }
        }

        // ---- Y: lane l -> y[t][pm][om] = W_lin[om] @ h_pm + b_lin[om] ----
        {
            const v2f* hq = (const v2f*)&s_h[slot][pm][0];
            const v2f* wq = (const v2f*)&s_wlin[om][0];
            v2f ya = v2f{yb, 0.0f};
            #pragma unroll
            for (int k = 0; k < 5; ++k)
                ya = __builtin_elementwise_fma(wq[k], hq[k], ya);
            float yv = ya.x + ya.y;
            outb[t * PN * OUTN + l] = yv;
            if (l < 4) s_y[slot][l] = yv;   // pm==0: feed next MAIN's y_prev
        }
        __builtin_amdgcn_wave_barrier();
    }

    // ---- final cell state c: [1, B, HID] appended after final_output ----
    if (odd) out[(long)BN * TPN * PN * OUTN + (long)batch * HIDN + m] = cm;
}

extern "C" void kernel_launch(void* const* d_in, const int* in_sizes, int n_in,
                              void* d_out, int out_size, void* d_ws, size_t ws_size,
                              hipStream_t stream) {
    const float* x     = (const float*)d_in[0];
    const float* W_ih  = (const float*)d_in[1];
    const float* W_hh  = (const float*)d_in[2];
    const float* b_ih  = (const float*)d_in[3];
    const float* b_hh  = (const float*)d_in[4];
    const float* W_lin = (const float*)d_in[5];
    const float* b_lin = (const float*)d_in[6];
    float* out = (float*)d_out;

    const int grid = (BN + GPB - 1) / GPB;  // 2731 blocks of 128 threads
    lstm_ar_kernel<<<grid, 128, 0, stream>>>(x, W_ih, W_hh, b_ih, b_hh, W_lin, b_lin, out);
}